// Round 20
// baseline (215.629 us; speedup 1.0000x reference)
//
#include <hip/hip_runtime.h>
#include <hip/hip_bf16.h>

typedef __attribute__((ext_vector_type(8))) __bf16 bf16x8;
typedef __attribute__((ext_vector_type(4))) float f32x4;

#define F_DIM 512
#define D_DIM 128
#define RPB 128            // rows per bucket (bucket = row >> 7)
#define MAXBUK 1024
#define BIN_CHUNK 8192
#define CAPMAX 3072        // >= runtime cap (2813); LDS sizing

__device__ __forceinline__ unsigned short f32_to_bf16_rn(float x) {
    union { float f; unsigned u; } v; v.f = x;
    unsigned u = v.u;
    unsigned rounded = u + 0x7fffu + ((u >> 16) & 1u);
    return (unsigned short)(rounded >> 16);
}
__device__ __forceinline__ float bf16_to_f32(unsigned short u) {
    return __uint_as_float((unsigned)u << 16);
}

// Wt transpose-convert only (cursor/rowcnt are hipMemsetAsync'ed)
__global__ void prep_kernel(const float* __restrict__ W, unsigned short* __restrict__ Wt) {
    int idx = blockIdx.x * 256 + threadIdx.x;   // 65536 total
    int n = idx >> 9;
    int k = idx & 511;
    Wt[idx] = f32_to_bf16_rn(W[k * D_DIM + n]);
}

// FUSED co-scheduled kernel: blocks [0, binBlocks) run the edge-binning
// path; blocks [binBlocks, ...) run the gemm path (R12/R19 structure).
// NEW: the bin path also produces PER-ROW edge counts (one global
// atomicAdd per edge, co-scheduled -> hidden in gemm latency bubbles),
// so sortaccum can skip its entire counting pass.
__global__ __launch_bounds__(256) void fused_gemm_bin(
    const float* __restrict__ A, const unsigned short* __restrict__ Bt,
    unsigned short* __restrict__ Sb, int Nrows,
    const int* __restrict__ ei, const float* __restrict__ ev,
    int* __restrict__ cursor, int* __restrict__ rowcnt,
    uint2* __restrict__ ecv, int E, int nbuk,
    int cap, int binBlocks)
{
    __shared__ __align__(16) char smem[30720];
    const int tid = threadIdx.x;

    if ((int)blockIdx.x < binBlocks) {
        // ---------------- bin path (cursor/rowcnt start zeroed) ----------------
        int* cnt = (int*)smem;
        int* bas = (int*)(smem + 4096);
        const int e0 = blockIdx.x * BIN_CHUNK;
        const int e1 = min(e0 + BIN_CHUNK, E);

        for (int i = tid; i < nbuk; i += 256) cnt[i] = 0;
        __syncthreads();
        for (int e = e0 + tid; e < e1; e += 256)
            atomicAdd(&cnt[ei[e] >> 7], 1);
        __syncthreads();
        for (int i = tid; i < nbuk; i += 256) {
            int c = cnt[i];
            bas[i] = c ? (i * cap + atomicAdd(&cursor[i], c)) : 0;
            cnt[i] = 0;
        }
        __syncthreads();
        for (int e = e0 + tid; e < e1; e += 256) {
            int r = ei[e];
            int b = r >> 7;
            int slot = atomicAdd(&cnt[b], 1);
            atomicAdd(&rowcnt[r], 1);          // per-row count for sortaccum
            uint2 cv;
            cv.x = ((unsigned)ei[E + e] << 7) | (unsigned)(r & 127);
            cv.y = __float_as_uint(ev[e]);
            ecv[(size_t)bas[b] + slot] = cv;
        }
        return;
    }

    // ---------------- gemm path (R12 structure, NT A loads) ----------------
    unsigned short* Al = (unsigned short*)smem;            // 2*64*40  = 10240 B
    unsigned short* Bl = (unsigned short*)(smem + 10240);  // 2*128*40 = 20480 B

    const int gb   = blockIdx.x - binBlocks;
    const int wave = tid >> 6;
    const int lane = tid & 63;
    const int g    = lane >> 4;
    const int r16  = lane & 15;
    const int m0   = gb * 64;

    const int sar = tid >> 2;
    const int skq = tid & 3;
    int arow = m0 + sar;
    if (arow >= Nrows) arow = Nrows - 1;
    const float* aptr = A + (size_t)arow * F_DIM + skq * 8;
    const int awoff = sar * 40 + skq * 8;

    const int sbr = tid >> 1;
    const int skh = tid & 1;
    const unsigned short* bptr = Bt + (size_t)sbr * F_DIM + skh * 16;
    const int bwoff = sbr * 40 + skh * 16;

    // two named register sets (static, rule #20)
    f32x4 a0_0, a0_1; uint4 b0_0, b0_1;   // set 0
    f32x4 a1_0, a1_1; uint4 b1_0, b1_1;   // set 1

#define LOADSET(aR0, aR1, bR0, bR1, ks) { \
    const f32x4* pa = (const f32x4*)(aptr + (ks) * 32); \
    aR0 = __builtin_nontemporal_load(pa); \
    aR1 = __builtin_nontemporal_load(pa + 1); \
    const uint4* pb = (const uint4*)(bptr + (ks) * 32); \
    bR0 = pb[0]; bR1 = pb[1]; }

#define STORESET(aR0, aR1, bR0, bR1, buf) { \
    union { uint4 q; __bf16 h[8]; } u; \
    u.h[0]=(__bf16)aR0[0]; u.h[1]=(__bf16)aR0[1]; u.h[2]=(__bf16)aR0[2]; u.h[3]=(__bf16)aR0[3]; \
    u.h[4]=(__bf16)aR1[0]; u.h[5]=(__bf16)aR1[1]; u.h[6]=(__bf16)aR1[2]; u.h[7]=(__bf16)aR1[3]; \
    *(uint4*)&Al[(buf) * 2560 + awoff] = u.q; \
    unsigned short* bw = &Bl[(buf) * 5120 + bwoff]; \
    *(uint4*)bw       = bR0; \
    *(uint4*)(bw + 8) = bR1; }

    f32x4 acc[8];
#pragma unroll
    for (int j = 0; j < 8; ++j) acc[j] = (f32x4)0.0f;

    // prologue: K0 staged; K1 (set1) and K2 (set0) in flight
    LOADSET(a0_0, a0_1, b0_0, b0_1, 0);
    STORESET(a0_0, a0_1, b0_0, b0_1, 0);
    LOADSET(a1_0, a1_1, b1_0, b1_1, 1);
    LOADSET(a0_0, a0_1, b0_0, b0_1, 2);
    asm volatile("s_waitcnt lgkmcnt(0)" ::: "memory");
    __builtin_amdgcn_s_barrier();

#pragma unroll
    for (int ks = 0; ks < 16; ++ks) {
        const unsigned short* Ab = Al + (ks & 1) * 2560;
        const unsigned short* Bb = Bl + (ks & 1) * 5120;
        bf16x8 af = *(const bf16x8*)&Ab[(wave * 16 + r16) * 40 + g * 8];
#pragma unroll
        for (int nf = 0; nf < 8; ++nf) {
            bf16x8 bf = *(const bf16x8*)&Bb[(nf * 16 + r16) * 40 + g * 8];
            acc[nf] = __builtin_amdgcn_mfma_f32_16x16x32_bf16(af, bf, acc[nf], 0, 0, 0);
        }

        if (ks < 15) {
            if ((ks & 1) == 0) {
                STORESET(a1_0, a1_1, b1_0, b1_1, (ks + 1) & 1);
                if (ks + 3 < 16) LOADSET(a1_0, a1_1, b1_0, b1_1, ks + 3);
            } else {
                STORESET(a0_0, a0_1, b0_0, b0_1, (ks + 1) & 1);
                if (ks + 3 < 16) LOADSET(a0_0, a0_1, b0_0, b0_1, ks + 3);
            }
        }
        asm volatile("s_waitcnt lgkmcnt(0)" ::: "memory");
        __builtin_amdgcn_s_barrier();
    }
#undef LOADSET
#undef STORESET

#pragma unroll
    for (int nf = 0; nf < 8; ++nf) {
#pragma unroll
        for (int r = 0; r < 4; ++r) {
            int row = m0 + wave * 16 + g * 4 + r;
            if (row < Nrows) {
                float v = acc[nf][r];
                Sb[(size_t)row * D_DIM + nf * 16 + r16] = f32_to_bf16_rn(v > 0.f ? v : 0.f);
            }
        }
    }
}

// FUSED sort+accumulate: one block per bucket, 512 threads, 8 waves.
// NEW: per-row counts come pre-computed from the bin phase (rowcnt) —
// the former counting pass (full ecv sweep + 1.6M LDS atomics) is gone.
// Single ecv sweep scatters into sorted LDS, then gather-accumulate.
__global__ __launch_bounds__(512) void sortaccum_kernel(
    const uint2* __restrict__ ecv, const int* __restrict__ cursor,
    const int* __restrict__ rowcnt,
    const unsigned short* __restrict__ Sb, const float* __restrict__ bias,
    float* __restrict__ out, int Nrows, int cap)
{
    __shared__ uint2 srt[CAPMAX];   // 24 KB
    __shared__ int cnt[RPB];
    __shared__ int base[RPB];
    __shared__ int scur[RPB];

    const int tid = threadIdx.x;
    const int b   = blockIdx.x;
    const int beg = b * cap;
    const int r0g = b * RPB;
    int n = cursor[b];                    // count (cursor started at 0)
    if (n > cap) n = cap;

    if (tid < RPB) {
        int r = r0g + tid;
        cnt[tid] = (r < Nrows) ? rowcnt[r] : 0;
    }
    __syncthreads();
    if (tid < 64) {
        int carry = 0;
#pragma unroll
        for (int c = 0; c < 2; ++c) {
            int idx = c * 64 + tid;
            int v = cnt[idx];
            int orig = v;
            for (int d = 1; d < 64; d <<= 1) {
                int t = __shfl_up(v, d, 64);
                if (tid >= d) v += t;
            }
            int excl = carry + v - orig;
            base[idx] = excl;
            scur[idx] = excl;
            carry += __shfl(v, 63, 64);
        }
    }
    __syncthreads();
    for (int i = tid; i < n; i += 512) {
        uint2 cv = ecv[beg + i];
        int slot = atomicAdd(&scur[cv.x & 127], 1);
        srt[slot] = cv;
    }
    __syncthreads();

    const int wv   = tid >> 6;
    const int lane = tid & 63;
    const int c2   = lane * 2;

#define GATHER(J) \
    uint2 cv##J = srt[i + J]; \
    ushort2 sv##J = *(const ushort2*)&Sb[(size_t)(cv##J.x >> 7) * D_DIM + c2];

#define ACCUM(J) { \
    float v = __uint_as_float(cv##J.y); \
    float sel = ((int)(cv##J.x & 127) == rl0) ? 1.f : 0.f; \
    float px = v * bf16_to_f32(sv##J.x); \
    float py = v * bf16_to_f32(sv##J.y); \
    ax0 += sel * px; ay0 += sel * py; \
    ax1 += px - sel * px; ay1 += py - sel * py; }

    for (int rr = 0; rr < 16; rr += 2) {
        const int rl0 = wv * 16 + rr;
        const int s  = base[rl0];
        const int e  = s + cnt[rl0] + cnt[rl0 + 1];

        float ax0 = 0.f, ay0 = 0.f, ax1 = 0.f, ay1 = 0.f;
        int i = s;
        for (; i + 7 < e; i += 8) {
            GATHER(0) GATHER(1) GATHER(2) GATHER(3)
            GATHER(4) GATHER(5) GATHER(6) GATHER(7)
            ACCUM(0) ACCUM(1) ACCUM(2) ACCUM(3)
            ACCUM(4) ACCUM(5) ACCUM(6) ACCUM(7)
        }
        for (; i < e; ++i) {
            GATHER(0)
            ACCUM(0)
        }

        int row0 = r0g + rl0;
        if (row0 < Nrows) {
            ushort2 so = *(const ushort2*)&Sb[(size_t)row0 * D_DIM + c2];
            float2 bv = *(const float2*)&bias[c2];
            float2 o;
            o.x = ax0 + bf16_to_f32(so.x) + bv.x;
            o.y = ay0 + bf16_to_f32(so.y) + bv.y;
            *(float2*)&out[(size_t)row0 * D_DIM + c2] = o;
        }
        int row1 = row0 + 1;
        if (row1 < Nrows) {
            ushort2 so = *(const ushort2*)&Sb[(size_t)row1 * D_DIM + c2];
            float2 bv = *(const float2*)&bias[c2];
            float2 o;
            o.x = ax1 + bf16_to_f32(so.x) + bv.x;
            o.y = ay1 + bf16_to_f32(so.y) + bv.y;
            *(float2*)&out[(size_t)row1 * D_DIM + c2] = o;
        }
    }
#undef GATHER
#undef ACCUM
}

extern "C" void kernel_launch(void* const* d_in, const int* in_sizes, int n_in,
                              void* d_out, int out_size, void* d_ws, size_t ws_size,
                              hipStream_t stream) {
    const float* feature = (const float*)d_in[0];
    const float* W       = (const float*)d_in[1];
    const float* bias    = (const float*)d_in[2];
    const float* ev      = (const float*)d_in[3];
    const int*   ei      = (const int*)d_in[4];
    float* out = (float*)d_out;

    const int N = in_sizes[0] / F_DIM;   // 100000
    const int E = in_sizes[3];           // 1600000
    const int nbuk = (N + RPB - 1) / RPB;            // 782
    int cap = (E + nbuk - 1) / nbuk;
    cap = cap + cap / 4 + 256;                       // ~2813 (<= CAPMAX)
    if (cap > CAPMAX) cap = CAPMAX;

    char* ws = (char*)d_ws;
    size_t cur = 0;
    auto alloc = [&](size_t bytes) -> void* {
        void* p = ws + cur;
        cur = (cur + bytes + 255) & ~(size_t)255;
        return p;
    };
    unsigned short* Sb     = (unsigned short*)alloc((size_t)N * D_DIM * 2);
    unsigned short* Wt     = (unsigned short*)alloc((size_t)D_DIM * F_DIM * 2);
    int*            cursor = (int*)alloc((size_t)nbuk * 4);
    int*            rowcnt = (int*)alloc((size_t)N * 4);
    uint2*          ecv    = (uint2*)alloc(((size_t)nbuk * cap + BIN_CHUNK) * 8);
    (void)ws_size;

    const int binBlocks  = (E + BIN_CHUNK - 1) / BIN_CHUNK;   // 196
    const int gemmBlocks = (N + 63) / 64;                     // 1563

    (void)hipMemsetAsync(cursor, 0, (size_t)nbuk * 4, stream);
    (void)hipMemsetAsync(rowcnt, 0, (size_t)N * 4, stream);
    prep_kernel<<<256, 256, 0, stream>>>(W, Wt);
    fused_gemm_bin<<<binBlocks + gemmBlocks, 256, 0, stream>>>(
        feature, Wt, Sb, N, ei, ev, cursor, rowcnt, ecv, E, nbuk, cap, binBlocks);
    sortaccum_kernel<<<nbuk, 512, 0, stream>>>(ecv, cursor, rowcnt, Sb, bias, out, N, cap);
}

// Round 21
// 179.115 us; speedup vs baseline: 1.2039x; 1.2039x over previous
//
#include <hip/hip_runtime.h>
#include <hip/hip_bf16.h>

typedef __attribute__((ext_vector_type(8))) __bf16 bf16x8;
typedef __attribute__((ext_vector_type(4))) float f32x4;

#define F_DIM 512
#define D_DIM 128
#define RPB 128            // rows per bucket (bucket = row >> 7)
#define MAXBUK 1024
#define BIN_CHUNK 8192
#define CAPMAX 3072        // >= runtime cap (2813); LDS sizing

__device__ __forceinline__ unsigned short f32_to_bf16_rn(float x) {
    union { float f; unsigned u; } v; v.f = x;
    unsigned u = v.u;
    unsigned rounded = u + 0x7fffu + ((u >> 16) & 1u);
    return (unsigned short)(rounded >> 16);
}
__device__ __forceinline__ float bf16_to_f32(unsigned short u) {
    return __uint_as_float((unsigned)u << 16);
}

// Wt transpose-convert only (cursor is hipMemsetAsync'ed)
__global__ void prep_kernel(const float* __restrict__ W, unsigned short* __restrict__ Wt) {
    int idx = blockIdx.x * 256 + threadIdx.x;   // 65536 total
    int n = idx >> 9;
    int k = idx & 511;
    Wt[idx] = f32_to_bf16_rn(W[k * D_DIM + n]);
}

// FUSED co-scheduled kernel: blocks [0, binBlocks) run the edge-binning
// path; blocks [binBlocks, ...) run the gemm path (R12 structure — the
// measured-best configuration).
// GEMM: 64(M)x128(N) tile, BK=32, depth-2 named-register prefetch, raw
// s_barrier + lgkmcnt(0) (no vmcnt drain). A loads are NON-TEMPORAL (via
// ext-vector f32x4 pointers) — A is a 205 MB single-use stream; keeping it
// out of L2 preserves Wt (re-read 128 KB/block) and edge-data residency.
__global__ __launch_bounds__(256) void fused_gemm_bin(
    const float* __restrict__ A, const unsigned short* __restrict__ Bt,
    unsigned short* __restrict__ Sb, int Nrows,
    const int* __restrict__ ei, const float* __restrict__ ev,
    int* __restrict__ cursor, uint2* __restrict__ ecv, int E, int nbuk,
    int cap, int binBlocks)
{
    __shared__ __align__(16) char smem[30720];
    const int tid = threadIdx.x;

    if ((int)blockIdx.x < binBlocks) {
        // ---------------- bin path (cursor starts zeroed) ----------------
        int* cnt = (int*)smem;
        int* bas = (int*)(smem + 4096);
        const int e0 = blockIdx.x * BIN_CHUNK;
        const int e1 = min(e0 + BIN_CHUNK, E);

        for (int i = tid; i < nbuk; i += 256) cnt[i] = 0;
        __syncthreads();
        for (int e = e0 + tid; e < e1; e += 256)
            atomicAdd(&cnt[ei[e] >> 7], 1);
        __syncthreads();
        for (int i = tid; i < nbuk; i += 256) {
            int c = cnt[i];
            bas[i] = c ? (i * cap + atomicAdd(&cursor[i], c)) : 0;
            cnt[i] = 0;
        }
        __syncthreads();
        for (int e = e0 + tid; e < e1; e += 256) {
            int r = ei[e];
            int b = r >> 7;
            int slot = atomicAdd(&cnt[b], 1);
            uint2 cv;
            cv.x = ((unsigned)ei[E + e] << 7) | (unsigned)(r & 127);
            cv.y = __float_as_uint(ev[e]);
            ecv[(size_t)bas[b] + slot] = cv;
        }
        return;
    }

    // ---------------- gemm path (R12 structure) ----------------
    unsigned short* Al = (unsigned short*)smem;            // 2*64*40  = 10240 B
    unsigned short* Bl = (unsigned short*)(smem + 10240);  // 2*128*40 = 20480 B

    const int gb   = blockIdx.x - binBlocks;
    const int wave = tid >> 6;
    const int lane = tid & 63;
    const int g    = lane >> 4;
    const int r16  = lane & 15;
    const int m0   = gb * 64;

    const int sar = tid >> 2;
    const int skq = tid & 3;
    int arow = m0 + sar;
    if (arow >= Nrows) arow = Nrows - 1;
    const float* aptr = A + (size_t)arow * F_DIM + skq * 8;
    const int awoff = sar * 40 + skq * 8;

    const int sbr = tid >> 1;
    const int skh = tid & 1;
    const unsigned short* bptr = Bt + (size_t)sbr * F_DIM + skh * 16;
    const int bwoff = sbr * 40 + skh * 16;

    // two named register sets (static, rule #20)
    f32x4 a0_0, a0_1; uint4 b0_0, b0_1;   // set 0
    f32x4 a1_0, a1_1; uint4 b1_0, b1_1;   // set 1

#define LOADSET(aR0, aR1, bR0, bR1, ks) { \
    const f32x4* pa = (const f32x4*)(aptr + (ks) * 32); \
    aR0 = __builtin_nontemporal_load(pa); \
    aR1 = __builtin_nontemporal_load(pa + 1); \
    const uint4* pb = (const uint4*)(bptr + (ks) * 32); \
    bR0 = pb[0]; bR1 = pb[1]; }

#define STORESET(aR0, aR1, bR0, bR1, buf) { \
    union { uint4 q; __bf16 h[8]; } u; \
    u.h[0]=(__bf16)aR0[0]; u.h[1]=(__bf16)aR0[1]; u.h[2]=(__bf16)aR0[2]; u.h[3]=(__bf16)aR0[3]; \
    u.h[4]=(__bf16)aR1[0]; u.h[5]=(__bf16)aR1[1]; u.h[6]=(__bf16)aR1[2]; u.h[7]=(__bf16)aR1[3]; \
    *(uint4*)&Al[(buf) * 2560 + awoff] = u.q; \
    unsigned short* bw = &Bl[(buf) * 5120 + bwoff]; \
    *(uint4*)bw       = bR0; \
    *(uint4*)(bw + 8) = bR1; }

    f32x4 acc[8];
#pragma unroll
    for (int j = 0; j < 8; ++j) acc[j] = (f32x4)0.0f;

    // prologue: K0 staged; K1 (set1) and K2 (set0) in flight
    LOADSET(a0_0, a0_1, b0_0, b0_1, 0);
    STORESET(a0_0, a0_1, b0_0, b0_1, 0);
    LOADSET(a1_0, a1_1, b1_0, b1_1, 1);
    LOADSET(a0_0, a0_1, b0_0, b0_1, 2);
    asm volatile("s_waitcnt lgkmcnt(0)" ::: "memory");
    __builtin_amdgcn_s_barrier();

#pragma unroll
    for (int ks = 0; ks < 16; ++ks) {
        const unsigned short* Ab = Al + (ks & 1) * 2560;
        const unsigned short* Bb = Bl + (ks & 1) * 5120;
        bf16x8 af = *(const bf16x8*)&Ab[(wave * 16 + r16) * 40 + g * 8];
#pragma unroll
        for (int nf = 0; nf < 8; ++nf) {
            bf16x8 bf = *(const bf16x8*)&Bb[(nf * 16 + r16) * 40 + g * 8];
            acc[nf] = __builtin_amdgcn_mfma_f32_16x16x32_bf16(af, bf, acc[nf], 0, 0, 0);
        }

        if (ks < 15) {
            if ((ks & 1) == 0) {
                // set1 holds K(ks+1): store it, then refill set1 with K(ks+3)
                STORESET(a1_0, a1_1, b1_0, b1_1, (ks + 1) & 1);
                if (ks + 3 < 16) LOADSET(a1_0, a1_1, b1_0, b1_1, ks + 3);
            } else {
                STORESET(a0_0, a0_1, b0_0, b0_1, (ks + 1) & 1);
                if (ks + 3 < 16) LOADSET(a0_0, a0_1, b0_0, b0_1, ks + 3);
            }
        }
        asm volatile("s_waitcnt lgkmcnt(0)" ::: "memory");
        __builtin_amdgcn_s_barrier();
    }
#undef LOADSET
#undef STORESET

#pragma unroll
    for (int nf = 0; nf < 8; ++nf) {
#pragma unroll
        for (int r = 0; r < 4; ++r) {
            int row = m0 + wave * 16 + g * 4 + r;
            if (row < Nrows) {
                float v = acc[nf][r];
                Sb[(size_t)row * D_DIM + nf * 16 + r16] = f32_to_bf16_rn(v > 0.f ? v : 0.f);
            }
        }
    }
}

// FUSED sort+accumulate: one block per bucket, 512 threads, 8 waves.
// No raw[] LDS staging — ecv is read twice from L2/L3 (17.6 MB, bin-hot).
// LDS 53.5 -> 25.6 KB moves the limiter from LDS (2 blocks/CU) to waves
// (4 blocks/CU): 2x resident waves for the gather-latency phase.
__global__ __launch_bounds__(512) void sortaccum_kernel(
    const uint2* __restrict__ ecv, const int* __restrict__ cursor,
    const unsigned short* __restrict__ Sb, const float* __restrict__ bias,
    float* __restrict__ out, int Nrows, int cap)
{
    __shared__ uint2 srt[CAPMAX];   // 24 KB
    __shared__ int cnt[RPB];
    __shared__ int base[RPB];
    __shared__ int scur[RPB];

    const int tid = threadIdx.x;
    const int b   = blockIdx.x;
    const int beg = b * cap;
    int n = cursor[b];                    // count (cursor started at 0)
    if (n > cap) n = cap;

    if (tid < RPB) cnt[tid] = 0;
    __syncthreads();
    for (int i = tid; i < n; i += 512)
        atomicAdd(&cnt[ecv[beg + i].x & 127], 1);
    __syncthreads();
    if (tid < 64) {
        int carry = 0;
#pragma unroll
        for (int c = 0; c < 2; ++c) {
            int idx = c * 64 + tid;
            int v = cnt[idx];
            int orig = v;
            for (int d = 1; d < 64; d <<= 1) {
                int t = __shfl_up(v, d, 64);
                if (tid >= d) v += t;
            }
            int excl = carry + v - orig;
            base[idx] = excl;
            scur[idx] = excl;
            carry += __shfl(v, 63, 64);
        }
    }
    __syncthreads();
    for (int i = tid; i < n; i += 512) {
        uint2 cv = ecv[beg + i];          // second read: L2/L3-hot
        int slot = atomicAdd(&scur[cv.x & 127], 1);
        srt[slot] = cv;
    }
    __syncthreads();

    const int wv   = tid >> 6;
    const int lane = tid & 63;
    const int c2   = lane * 2;
    const int r0g  = b * RPB;

#define GATHER(J) \
    uint2 cv##J = srt[i + J]; \
    ushort2 sv##J = *(const ushort2*)&Sb[(size_t)(cv##J.x >> 7) * D_DIM + c2];

#define ACCUM(J) { \
    float v = __uint_as_float(cv##J.y); \
    float sel = ((int)(cv##J.x & 127) == rl0) ? 1.f : 0.f; \
    float px = v * bf16_to_f32(sv##J.x); \
    float py = v * bf16_to_f32(sv##J.y); \
    ax0 += sel * px; ay0 += sel * py; \
    ax1 += px - sel * px; ay1 += py - sel * py; }

    for (int rr = 0; rr < 16; rr += 2) {
        const int rl0 = wv * 16 + rr;
        const int s  = base[rl0];
        const int e  = s + cnt[rl0] + cnt[rl0 + 1];

        float ax0 = 0.f, ay0 = 0.f, ax1 = 0.f, ay1 = 0.f;
        int i = s;
        for (; i + 7 < e; i += 8) {
            GATHER(0) GATHER(1) GATHER(2) GATHER(3)
            GATHER(4) GATHER(5) GATHER(6) GATHER(7)
            ACCUM(0) ACCUM(1) ACCUM(2) ACCUM(3)
            ACCUM(4) ACCUM(5) ACCUM(6) ACCUM(7)
        }
        for (; i < e; ++i) {
            GATHER(0)
            ACCUM(0)
        }

        int row0 = r0g + rl0;
        if (row0 < Nrows) {
            ushort2 so = *(const ushort2*)&Sb[(size_t)row0 * D_DIM + c2];
            float2 bv = *(const float2*)&bias[c2];
            float2 o;
            o.x = ax0 + bf16_to_f32(so.x) + bv.x;
            o.y = ay0 + bf16_to_f32(so.y) + bv.y;
            *(float2*)&out[(size_t)row0 * D_DIM + c2] = o;
        }
        int row1 = row0 + 1;
        if (row1 < Nrows) {
            ushort2 so = *(const ushort2*)&Sb[(size_t)row1 * D_DIM + c2];
            float2 bv = *(const float2*)&bias[c2];
            float2 o;
            o.x = ax1 + bf16_to_f32(so.x) + bv.x;
            o.y = ay1 + bf16_to_f32(so.y) + bv.y;
            *(float2*)&out[(size_t)row1 * D_DIM + c2] = o;
        }
    }
#undef GATHER
#undef ACCUM
}

extern "C" void kernel_launch(void* const* d_in, const int* in_sizes, int n_in,
                              void* d_out, int out_size, void* d_ws, size_t ws_size,
                              hipStream_t stream) {
    const float* feature = (const float*)d_in[0];
    const float* W       = (const float*)d_in[1];
    const float* bias    = (const float*)d_in[2];
    const float* ev      = (const float*)d_in[3];
    const int*   ei      = (const int*)d_in[4];
    float* out = (float*)d_out;

    const int N = in_sizes[0] / F_DIM;   // 100000
    const int E = in_sizes[3];           // 1600000
    const int nbuk = (N + RPB - 1) / RPB;            // 782
    int cap = (E + nbuk - 1) / nbuk;
    cap = cap + cap / 4 + 256;                       // ~2813 (<= CAPMAX)
    if (cap > CAPMAX) cap = CAPMAX;

    char* ws = (char*)d_ws;
    size_t cur = 0;
    auto alloc = [&](size_t bytes) -> void* {
        void* p = ws + cur;
        cur = (cur + bytes + 255) & ~(size_t)255;
        return p;
    };
    unsigned short* Sb     = (unsigned short*)alloc((size_t)N * D_DIM * 2);
    unsigned short* Wt     = (unsigned short*)alloc((size_t)D_DIM * F_DIM * 2);
    int*            cursor = (int*)alloc((size_t)nbuk * 4);
    uint2*          ecv    = (uint2*)alloc(((size_t)nbuk * cap + BIN_CHUNK) * 8);
    (void)ws_size;

    const int binBlocks  = (E + BIN_CHUNK - 1) / BIN_CHUNK;   // 196
    const int gemmBlocks = (N + 63) / 64;                     // 1563

    (void)hipMemsetAsync(cursor, 0, (size_t)nbuk * 4, stream);
    prep_kernel<<<256, 256, 0, stream>>>(W, Wt);
    fused_gemm_bin<<<binBlocks + gemmBlocks, 256, 0, stream>>>(
        feature, Wt, Sb, N, ei, ev, cursor, ecv, E, nbuk, cap, binBlocks);
    sortaccum_kernel<<<nbuk, 512, 0, stream>>>(ecv, cursor, Sb, bias, out, N, cap);
}